// Round 8
// baseline (657.164 us; speedup 1.0000x reference)
//
#include <hip/hip_runtime.h>
#include <hip/hip_cooperative_groups.h>
#include <math.h>

namespace cg = cooperative_groups;

typedef float  f32x4  __attribute__((ext_vector_type(4)));
typedef short  bf16x8 __attribute__((ext_vector_type(8)));
typedef unsigned short u16x8 __attribute__((ext_vector_type(8)));
typedef unsigned short u16x4 __attribute__((ext_vector_type(4)));

#define B_ROWS 2048
#define D_DIM  512
#define W_DIM  512
#define N_NODES 63
#define N_BINS  64
#define K_TOT   32768   // 64 * 512
#define NSPLIT  16      // 4 l's per z-slot
#define LPS     (N_BINS / NSPLIT)   // 4
#define DEPS    1e-12f

__device__ __forceinline__ unsigned short f2bf(float f) {
    union { float f; unsigned int u; } v; v.f = f;
    unsigned int u = v.u;
    return (unsigned short)((u + 0x7fffu + ((u >> 16) & 1u)) >> 16);
}

__device__ __forceinline__ float sigmoidf_(float z) {
    return 1.0f / (1.0f + expf(-z));
}

__device__ __forceinline__ void load_lds16(const void* g, void* l) {
    __builtin_amdgcn_global_load_lds(
        (const __attribute__((address_space(1))) unsigned int*)g,
        (__attribute__((address_space(3))) unsigned int*)l,
        16, 0, 0);
}

// ======================= fused cooperative kernel ==========================
// phase 0: transpose T -> Tt (bf16, [n][k]) + prep (dist, xb)
// phase 1: online-rescaled dist-fold GEMM -> part[16][2048][512]
// phase 2: split reduction -> out
__global__ __launch_bounds__(256, 4) void k_fused(
    const float* __restrict__ x, const float* __restrict__ ray,
    const float* __restrict__ w_i, const float* __restrict__ b_i,
    const float* __restrict__ a_i, const int* __restrict__ idx,
    const float* __restrict__ T,
    float* __restrict__ dist, unsigned short* __restrict__ xb,
    unsigned short* __restrict__ Tt, float* __restrict__ part,
    float* __restrict__ out)
{
    __shared__ __align__(16) char smem[34816];
    unsigned short* As = (unsigned short*)smem;            // 16384 B
    unsigned short* Bs = (unsigned short*)(smem + 16384);  // 16384 B
    float*          Ds = (float*)(smem + 32768);           // 2048 B
    float (*tile)[65]  = (float (*)[65])smem;              // phase-0 scratch

    const int bid = blockIdx.x;
    const int t   = threadIdx.x;

    // ---------------- phase 0a: transpose (4 tile jobs per block) ----------
    {
        const int w4 = (t & 15) * 4;
        const int ir = t >> 4;     // 0..15
        for (int q = 0; q < 4; ++q) {
            const int job = bid * 4 + q;       // 0..4095
            const int i0 = (job & 7) * 64;
            const int w0 = ((job >> 3) & 7) * 64;
            const int l  = job >> 6;
            const float* src = T + ((size_t)(l * 512 + i0)) * 512 + w0;
#pragma unroll
            for (int p = 0; p < 4; ++p) {
                int i = ir + p * 16;
                f32x4 v = *(const f32x4*)(src + (size_t)i * 512 + w4);
                tile[i][w4 + 0] = v.x; tile[i][w4 + 1] = v.y;
                tile[i][w4 + 2] = v.z; tile[i][w4 + 3] = v.w;
            }
            __syncthreads();
#pragma unroll
            for (int rep = 0; rep < 2; ++rep) {
                int id = t + rep * 256;    // 0..511
                int w  = id >> 3;          // 0..63
                int c  = id & 7;           // i-chunk
                u16x8 o;
#pragma unroll
                for (int jj = 0; jj < 8; ++jj) o[jj] = f2bf(tile[c * 8 + jj][w]);
                *(u16x8*)(Tt + (size_t)(w0 + w) * K_TOT + l * 512 + i0 + c * 8) = o;
            }
            __syncthreads();   // tile reused next job
        }
    }

    // ---------------- phase 0b: prep (blocks < 512) ------------------------
    if (bid < 512) {
        const int wid  = t >> 6;
        const int lane = t & 63;
        const int row  = bid * 4 + wid;
        const float* xr = x + (size_t)row * D_DIM;

        float dotv = 0.f, xx = 0.f, rr = 0.f;
#pragma unroll
        for (int j = 0; j < 2; ++j) {
            f32x4 xv = *(const f32x4*)(xr  + j * 256 + lane * 4);
            f32x4 rv = *(const f32x4*)(ray + j * 256 + lane * 4);
            dotv += xv.x * rv.x + xv.y * rv.y + xv.z * rv.z + xv.w * rv.w;
            xx   += xv.x * xv.x + xv.y * xv.y + xv.z * xv.z + xv.w * xv.w;
            rr   += rv.x * rv.x + rv.y * rv.y + rv.z * rv.z + rv.w * rv.w;
            u16x4 o;
            o[0] = f2bf(xv.x); o[1] = f2bf(xv.y); o[2] = f2bf(xv.z); o[3] = f2bf(xv.w);
            *(u16x4*)(xb + (size_t)row * D_DIM + j * 256 + lane * 4) = o;
        }
#pragma unroll
        for (int off = 1; off < 64; off <<= 1) {
            dotv += __shfl_xor(dotv, off, 64);
            xx   += __shfl_xor(xx,   off, 64);
            rr   += __shfl_xor(rr,   off, 64);
        }
        float xn = fmaxf(sqrtf(xx), 1e-8f);
        float rn = fmaxf(sqrtf(rr), 1e-8f);
        float cosv = dotv / (xn * rn);
        cosv = fminf(1.f, fmaxf(-1.f, cosv));
        float angle = acosf(cosv) * 0.31830988618379067f; // 1/pi

        float dec = 0.f;
        if (lane < N_NODES) {
            float sw = sigmoidf_(w_i[lane]);
            float sb = sigmoidf_(b_i[lane]);
            float nf = (0.5f + sw) * angle - sb;
            dec = sigmoidf_(nf * (1.0f + a_i[lane]));
        }

        float p = 1.f;
#pragma unroll
        for (int v = 0; v < 6; ++v) {
            int j = idx[lane * 6 + v];
            int node = (j < N_NODES) ? j : j - N_NODES;
            float d = __shfl(dec, node, 64);
            p *= (j < N_NODES) ? d : (1.0f - d);
        }
        dist[(size_t)row * N_BINS + lane] = p;
    }

    __threadfence();
    cg::this_grid().sync();

    // ---------------- phase 1: GEMM ----------------------------------------
    {
        const int xcd = bid & 7;
        const int j   = bid >> 3;               // 0..127
        const int combo = xcd * 8 + (j >> 4);   // 0..63
        const int mblk  = j & 15;
        const int bm0 = mblk * 128;
        const int bn0 = (combo & 3) * 128;
        const int z   = combo >> 2;             // 0..15
        const int l0  = z * LPS;

        const int lane = t & 63;
        const int wid  = t >> 6;
        const int wm = wid >> 1, wn = wid & 1;
        const int lq = lane >> 4, lr = lane & 15;

        const int srow = t >> 3;   // 0..31 (+ j*32)
        const int c    = t & 7;    // LDS chunk slot

        if (t < 128) {
            f32x4 dv = *(const f32x4*)(dist + (size_t)(bm0 + t) * N_BINS + l0);
            *(f32x4*)&Ds[t * LPS] = dv;
        }
        __syncthreads();

        f32x4 acc[4][4];
#pragma unroll
        for (int a = 0; a < 4; ++a)
#pragma unroll
            for (int bb = 0; bb < 4; ++bb)
                acc[a][bb] = (f32x4){0.f, 0.f, 0.f, 0.f};

        for (int lo = 0; lo < LPS; ++lo) {
            const int l = l0 + lo;

            if (lo > 0) {
#pragma unroll
                for (int fm = 0; fm < 4; ++fm)
#pragma unroll
                    for (int r = 0; r < 4; ++r) {
                        int m = wm * 64 + fm * 16 + lq * 4 + r;
                        float dp = fmaxf(Ds[m * LPS + lo - 1], DEPS);
                        float dn = fmaxf(Ds[m * LPS + lo],     DEPS);
                        float ratio = dp * __builtin_amdgcn_rcpf(dn);
#pragma unroll
                        for (int fn = 0; fn < 4; ++fn)
                            acc[fm][fn][r] *= ratio;
                    }
            }

            for (int it = 0; it < 8; ++it) {
                const int i0 = it * 64;
#pragma unroll
                for (int jj = 0; jj < 4; ++jj) {
                    int row = srow + jj * 32;
                    int cg_ = c ^ (row & 7);
                    load_lds16(xb + (size_t)(bm0 + row) * D_DIM + i0 + cg_ * 8,
                               &As[row * 64 + c * 8]);
                    load_lds16(Tt + (size_t)(bn0 + row) * K_TOT + l * 512 + i0 + cg_ * 8,
                               &Bs[row * 64 + c * 8]);
                }
                __syncthreads();
#pragma unroll
                for (int ks = 0; ks < 2; ++ks) {
                    bf16x8 af[4], bfr[4];
#pragma unroll
                    for (int fm = 0; fm < 4; ++fm) {
                        int m = wm * 64 + fm * 16 + lr;
                        int g = ks * 4 + lq;
                        af[fm] = *(const bf16x8*)&As[m * 64 + ((g ^ (m & 7)) * 8)];
                    }
#pragma unroll
                    for (int fn = 0; fn < 4; ++fn) {
                        int n = wn * 64 + fn * 16 + lr;
                        int g = ks * 4 + lq;
                        bfr[fn] = *(const bf16x8*)&Bs[n * 64 + ((g ^ (n & 7)) * 8)];
                    }
#pragma unroll
                    for (int fm = 0; fm < 4; ++fm)
#pragma unroll
                        for (int fn = 0; fn < 4; ++fn)
                            acc[fm][fn] = __builtin_amdgcn_mfma_f32_16x16x32_bf16(
                                af[fm], bfr[fn], acc[fm][fn], 0, 0, 0);
                }
                __syncthreads();
            }
        }

        float* Cp = part + (size_t)z * (B_ROWS * W_DIM);
#pragma unroll
        for (int fm = 0; fm < 4; ++fm)
#pragma unroll
            for (int r = 0; r < 4; ++r) {
                int m = wm * 64 + fm * 16 + lq * 4 + r;
                float dl = fmaxf(Ds[m * LPS + LPS - 1], DEPS);
#pragma unroll
                for (int fn = 0; fn < 4; ++fn) {
                    int col = bn0 + wn * 64 + fn * 16 + lr;
                    Cp[(size_t)(bm0 + m) * W_DIM + col] = acc[fm][fn][r] * dl;
                }
            }
    }

    __threadfence();
    cg::this_grid().sync();

    // ---------------- phase 2: split reduction -----------------------------
    {
        int i = (bid * 256 + t) * 4;
        f32x4 s = *(const f32x4*)(part + i);
#pragma unroll
        for (int p = 1; p < NSPLIT; ++p)
            s += *(const f32x4*)(part + (size_t)p * (B_ROWS * W_DIM) + i);
        *(f32x4*)(out + i) = s;
    }
}

// ======================= fallback (R6) kernels =============================
__global__ __launch_bounds__(256) void k_pre(
    const float* __restrict__ x, const float* __restrict__ ray,
    const float* __restrict__ w_i, const float* __restrict__ b_i,
    const float* __restrict__ a_i, const int* __restrict__ idx,
    const float* __restrict__ T,
    float* __restrict__ dist, unsigned short* __restrict__ xb,
    unsigned short* __restrict__ Tt)
{
    __shared__ float tile[64][65];
    const int bid = blockIdx.x;
    const int t   = threadIdx.x;

    if (bid < 4096) {
        const int i0 = (bid & 7) * 64;
        const int w0 = ((bid >> 3) & 7) * 64;
        const int l  = bid >> 6;

        const int w4 = (t & 15) * 4;
        const int ir = t >> 4;
        const float* src = T + ((size_t)(l * 512 + i0)) * 512 + w0;
#pragma unroll
        for (int p = 0; p < 4; ++p) {
            int i = ir + p * 16;
            f32x4 v = *(const f32x4*)(src + (size_t)i * 512 + w4);
            tile[i][w4 + 0] = v.x; tile[i][w4 + 1] = v.y;
            tile[i][w4 + 2] = v.z; tile[i][w4 + 3] = v.w;
        }
        __syncthreads();
#pragma unroll
        for (int rep = 0; rep < 2; ++rep) {
            int id = t + rep * 256;
            int w  = id >> 3;
            int c  = id & 7;
            u16x8 o;
#pragma unroll
            for (int j = 0; j < 8; ++j) o[j] = f2bf(tile[c * 8 + j][w]);
            *(u16x8*)(Tt + (size_t)(w0 + w) * K_TOT + l * 512 + i0 + c * 8) = o;
        }
        return;
    }

    const int pb   = bid - 4096;
    const int wid  = t >> 6;
    const int lane = t & 63;
    const int row  = pb * 4 + wid;
    const float* xr = x + (size_t)row * D_DIM;

    float dotv = 0.f, xx = 0.f, rr = 0.f;
#pragma unroll
    for (int j = 0; j < 2; ++j) {
        f32x4 xv = *(const f32x4*)(xr  + j * 256 + lane * 4);
        f32x4 rv = *(const f32x4*)(ray + j * 256 + lane * 4);
        dotv += xv.x * rv.x + xv.y * rv.y + xv.z * rv.z + xv.w * rv.w;
        xx   += xv.x * xv.x + xv.y * xv.y + xv.z * xv.z + xv.w * xv.w;
        rr   += rv.x * rv.x + rv.y * rv.y + rv.z * rv.z + rv.w * rv.w;
        u16x4 o;
        o[0] = f2bf(xv.x); o[1] = f2bf(xv.y); o[2] = f2bf(xv.z); o[3] = f2bf(xv.w);
        *(u16x4*)(xb + (size_t)row * D_DIM + j * 256 + lane * 4) = o;
    }
#pragma unroll
    for (int off = 1; off < 64; off <<= 1) {
        dotv += __shfl_xor(dotv, off, 64);
        xx   += __shfl_xor(xx,   off, 64);
        rr   += __shfl_xor(rr,   off, 64);
    }
    float xn = fmaxf(sqrtf(xx), 1e-8f);
    float rn = fmaxf(sqrtf(rr), 1e-8f);
    float cosv = dotv / (xn * rn);
    cosv = fminf(1.f, fmaxf(-1.f, cosv));
    float angle = acosf(cosv) * 0.31830988618379067f;

    float dec = 0.f;
    if (lane < N_NODES) {
        float sw = sigmoidf_(w_i[lane]);
        float sb = sigmoidf_(b_i[lane]);
        float nf = (0.5f + sw) * angle - sb;
        dec = sigmoidf_(nf * (1.0f + a_i[lane]));
    }

    float p = 1.f;
#pragma unroll
    for (int v = 0; v < 6; ++v) {
        int j = idx[lane * 6 + v];
        int node = (j < N_NODES) ? j : j - N_NODES;
        float d = __shfl(dec, node, 64);
        p *= (j < N_NODES) ? d : (1.0f - d);
    }
    dist[(size_t)row * N_BINS + lane] = p;
}

__global__ __launch_bounds__(256, 4) void k_gemm6(
    const unsigned short* __restrict__ xb, const unsigned short* __restrict__ Tt,
    const float* __restrict__ dist, float* __restrict__ part)
{
    __shared__ unsigned short As[128 * 64];
    __shared__ unsigned short Bs[128 * 64];
    __shared__ float Ds[128 * LPS];

    const int b   = blockIdx.x;
    const int xcd = b & 7;
    const int j   = b >> 3;
    const int combo = xcd * 8 + (j >> 4);
    const int mblk  = j & 15;
    const int bm0 = mblk * 128;
    const int bn0 = (combo & 3) * 128;
    const int z   = combo >> 2;
    const int l0  = z * LPS;

    const int t    = threadIdx.x;
    const int lane = t & 63;
    const int wid  = t >> 6;
    const int wm = wid >> 1, wn = wid & 1;
    const int lq = lane >> 4, lr = lane & 15;

    const int srow = t >> 3;
    const int c    = t & 7;

    if (t < 128) {
        f32x4 dv = *(const f32x4*)(dist + (size_t)(bm0 + t) * N_BINS + l0);
        *(f32x4*)&Ds[t * LPS] = dv;
    }
    __syncthreads();

    f32x4 acc[4][4];
#pragma unroll
    for (int a = 0; a < 4; ++a)
#pragma unroll
        for (int bb = 0; bb < 4; ++bb)
            acc[a][bb] = (f32x4){0.f, 0.f, 0.f, 0.f};

    for (int lo = 0; lo < LPS; ++lo) {
        const int l = l0 + lo;
        if (lo > 0) {
#pragma unroll
            for (int fm = 0; fm < 4; ++fm)
#pragma unroll
                for (int r = 0; r < 4; ++r) {
                    int m = wm * 64 + fm * 16 + lq * 4 + r;
                    float dp = fmaxf(Ds[m * LPS + lo - 1], DEPS);
                    float dn = fmaxf(Ds[m * LPS + lo],     DEPS);
                    float ratio = dp * __builtin_amdgcn_rcpf(dn);
#pragma unroll
                    for (int fn = 0; fn < 4; ++fn)
                        acc[fm][fn][r] *= ratio;
                }
        }

        for (int it = 0; it < 8; ++it) {
            const int i0 = it * 64;
#pragma unroll
            for (int jj = 0; jj < 4; ++jj) {
                int row = srow + jj * 32;
                int cg_ = c ^ (row & 7);
                load_lds16(xb + (size_t)(bm0 + row) * D_DIM + i0 + cg_ * 8,
                           &As[row * 64 + c * 8]);
                load_lds16(Tt + (size_t)(bn0 + row) * K_TOT + l * 512 + i0 + cg_ * 8,
                           &Bs[row * 64 + c * 8]);
            }
            __syncthreads();
#pragma unroll
            for (int ks = 0; ks < 2; ++ks) {
                bf16x8 af[4], bfr[4];
#pragma unroll
                for (int fm = 0; fm < 4; ++fm) {
                    int m = wm * 64 + fm * 16 + lr;
                    int g = ks * 4 + lq;
                    af[fm] = *(const bf16x8*)&As[m * 64 + ((g ^ (m & 7)) * 8)];
                }
#pragma unroll
                for (int fn = 0; fn < 4; ++fn) {
                    int n = wn * 64 + fn * 16 + lr;
                    int g = ks * 4 + lq;
                    bfr[fn] = *(const bf16x8*)&Bs[n * 64 + ((g ^ (n & 7)) * 8)];
                }
#pragma unroll
                for (int fm = 0; fm < 4; ++fm)
#pragma unroll
                    for (int fn = 0; fn < 4; ++fn)
                        acc[fm][fn] = __builtin_amdgcn_mfma_f32_16x16x32_bf16(
                            af[fm], bfr[fn], acc[fm][fn], 0, 0, 0);
            }
            __syncthreads();
        }
    }

    float* Cp = part + (size_t)z * (B_ROWS * W_DIM);
#pragma unroll
    for (int fm = 0; fm < 4; ++fm)
#pragma unroll
        for (int r = 0; r < 4; ++r) {
            int m = wm * 64 + fm * 16 + lq * 4 + r;
            float dl = fmaxf(Ds[m * LPS + LPS - 1], DEPS);
#pragma unroll
            for (int fn = 0; fn < 4; ++fn) {
                int col = bn0 + wn * 64 + fn * 16 + lr;
                Cp[(size_t)(bm0 + m) * W_DIM + col] = acc[fm][fn][r] * dl;
            }
        }
}

__global__ __launch_bounds__(256) void k_reduce(
    const float* __restrict__ part, float* __restrict__ out, int nsplit)
{
    int i = (blockIdx.x * 256 + threadIdx.x) * 4;
    f32x4 s = *(const f32x4*)(part + i);
    for (int p = 1; p < nsplit; ++p)
        s += *(const f32x4*)(part + (size_t)p * (B_ROWS * W_DIM) + i);
    *(f32x4*)(out + i) = s;
}

extern "C" void kernel_launch(void* const* d_in, const int* in_sizes, int n_in,
                              void* d_out, int out_size, void* d_ws, size_t ws_size,
                              hipStream_t stream) {
    const float* x   = (const float*)d_in[0];
    const float* ray = (const float*)d_in[1];
    const float* w_i = (const float*)d_in[2];
    const float* b_i = (const float*)d_in[3];
    const float* a_i = (const float*)d_in[4];
    const float* T   = (const float*)d_in[5];
    const int*   idx = (const int*)d_in[6];
    float* out = (float*)d_out;

    char* ws = (char*)d_ws;
    const size_t distBytes = (size_t)B_ROWS * N_BINS * 4;        // 512 KiB
    const size_t xbBytes   = (size_t)B_ROWS * D_DIM * 2;         // 2 MiB
    const size_t ttBytes   = (size_t)W_DIM * K_TOT * 2;          // 32 MiB
    const size_t partBytes = (size_t)B_ROWS * W_DIM * 4;         // 4 MiB per split

    float*          dist = (float*)ws;
    unsigned short* xb   = (unsigned short*)(ws + distBytes);
    unsigned short* Tt   = (unsigned short*)(ws + distBytes + xbBytes);

    if (ws_size >= distBytes + xbBytes + ttBytes + (size_t)NSPLIT * partBytes) {
        float* part = (float*)(ws + distBytes + xbBytes + ttBytes);

        void* args[] = {
            (void*)&x, (void*)&ray, (void*)&w_i, (void*)&b_i, (void*)&a_i,
            (void*)&idx, (void*)&T, (void*)&dist, (void*)&xb, (void*)&Tt,
            (void*)&part, (void*)&out
        };
        hipError_t e = hipLaunchCooperativeKernel(
            (const void*)k_fused, dim3(1024), dim3(256), args, 0, stream);

        if (e != hipSuccess) {
            // fallback: R6 3-kernel pipeline
            k_pre<<<4096 + 512, 256, 0, stream>>>(x, ray, w_i, b_i, a_i, idx, T,
                                                  dist, xb, Tt);
            k_gemm6<<<1024, 256, 0, stream>>>(xb, Tt, dist, part);
            k_reduce<<<(B_ROWS * W_DIM) / (256 * 4), 256, 0, stream>>>(part, out, NSPLIT);
        }
    } else {
        // minimal-workspace fallback: 3-kernel pipeline with NSPLIT=1 semantics
        // (requires at least dist+xb+Tt+1 part; assume ws covers it)
        float* part = (float*)(ws + distBytes + xbBytes + ttBytes);
        k_pre<<<4096 + 512, 256, 0, stream>>>(x, ray, w_i, b_i, a_i, idx, T,
                                              dist, xb, Tt);
        k_gemm6<<<1024, 256, 0, stream>>>(xb, Tt, dist, part);
        k_reduce<<<(B_ROWS * W_DIM) / (256 * 4), 256, 0, stream>>>(part, out, NSPLIT);
    }
}

// Round 9
// 200.439 us; speedup vs baseline: 3.2786x; 3.2786x over previous
//
#include <hip/hip_runtime.h>
#include <math.h>

typedef float  f32x4  __attribute__((ext_vector_type(4)));
typedef float  f32x2  __attribute__((ext_vector_type(2)));
typedef short  bf16x8 __attribute__((ext_vector_type(8)));
typedef unsigned short u16x8 __attribute__((ext_vector_type(8)));
typedef unsigned short u16x4 __attribute__((ext_vector_type(4)));

#define B_ROWS 2048
#define D_DIM  512
#define W_DIM  512
#define N_NODES 63
#define N_BINS  64
#define K_TOT   32768   // 64 * 512
#define NSPLIT  16      // 4 l's per z-slot
#define LPS     (N_BINS / NSPLIT)   // 4
#define DEPS    1e-12f

__device__ __forceinline__ unsigned short f2bf(float f) {
    union { float f; unsigned int u; } v; v.f = f;
    unsigned int u = v.u;
    return (unsigned short)((u + 0x7fffu + ((u >> 16) & 1u)) >> 16);
}

__device__ __forceinline__ float sigmoidf_(float z) {
    return 1.0f / (1.0f + expf(-z));
}

__device__ __forceinline__ void load_lds16(const void* g, void* l) {
    __builtin_amdgcn_global_load_lds(
        (const __attribute__((address_space(1))) unsigned int*)g,
        (__attribute__((address_space(3))) unsigned int*)l,
        16, 0, 0);
}

// ---------------- kernel 1: fused prep (dist + xb) AND transpose (R6) ------
__global__ __launch_bounds__(256) void k_pre(
    const float* __restrict__ x, const float* __restrict__ ray,
    const float* __restrict__ w_i, const float* __restrict__ b_i,
    const float* __restrict__ a_i, const int* __restrict__ idx,
    const float* __restrict__ T,
    float* __restrict__ dist, unsigned short* __restrict__ xb,
    unsigned short* __restrict__ Tt)
{
    __shared__ float tile[64][65];
    const int bid = blockIdx.x;
    const int t   = threadIdx.x;

    if (bid < 4096) {
        const int i0 = (bid & 7) * 64;
        const int w0 = ((bid >> 3) & 7) * 64;
        const int l  = bid >> 6;

        const int w4 = (t & 15) * 4;
        const int ir = t >> 4;
        const float* src = T + ((size_t)(l * 512 + i0)) * 512 + w0;
#pragma unroll
        for (int p = 0; p < 4; ++p) {
            int i = ir + p * 16;
            f32x4 v = *(const f32x4*)(src + (size_t)i * 512 + w4);
            tile[i][w4 + 0] = v.x; tile[i][w4 + 1] = v.y;
            tile[i][w4 + 2] = v.z; tile[i][w4 + 3] = v.w;
        }
        __syncthreads();
#pragma unroll
        for (int rep = 0; rep < 2; ++rep) {
            int id = t + rep * 256;
            int w  = id >> 3;
            int c  = id & 7;
            u16x8 o;
#pragma unroll
            for (int j = 0; j < 8; ++j) o[j] = f2bf(tile[c * 8 + j][w]);
            *(u16x8*)(Tt + (size_t)(w0 + w) * K_TOT + l * 512 + i0 + c * 8) = o;
        }
        return;
    }

    const int pb   = bid - 4096;
    const int wid  = t >> 6;
    const int lane = t & 63;
    const int row  = pb * 4 + wid;
    const float* xr = x + (size_t)row * D_DIM;

    float dotv = 0.f, xx = 0.f, rr = 0.f;
#pragma unroll
    for (int j = 0; j < 2; ++j) {
        f32x4 xv = *(const f32x4*)(xr  + j * 256 + lane * 4);
        f32x4 rv = *(const f32x4*)(ray + j * 256 + lane * 4);
        dotv += xv.x * rv.x + xv.y * rv.y + xv.z * rv.z + xv.w * rv.w;
        xx   += xv.x * xv.x + xv.y * xv.y + xv.z * xv.z + xv.w * xv.w;
        rr   += rv.x * rv.x + rv.y * rv.y + rv.z * rv.z + rv.w * rv.w;
        u16x4 o;
        o[0] = f2bf(xv.x); o[1] = f2bf(xv.y); o[2] = f2bf(xv.z); o[3] = f2bf(xv.w);
        *(u16x4*)(xb + (size_t)row * D_DIM + j * 256 + lane * 4) = o;
    }
#pragma unroll
    for (int off = 1; off < 64; off <<= 1) {
        dotv += __shfl_xor(dotv, off, 64);
        xx   += __shfl_xor(xx,   off, 64);
        rr   += __shfl_xor(rr,   off, 64);
    }
    float xn = fmaxf(sqrtf(xx), 1e-8f);
    float rn = fmaxf(sqrtf(rr), 1e-8f);
    float cosv = dotv / (xn * rn);
    cosv = fminf(1.f, fmaxf(-1.f, cosv));
    float angle = acosf(cosv) * 0.31830988618379067f;

    float dec = 0.f;
    if (lane < N_NODES) {
        float sw = sigmoidf_(w_i[lane]);
        float sb = sigmoidf_(b_i[lane]);
        float nf = (0.5f + sw) * angle - sb;
        dec = sigmoidf_(nf * (1.0f + a_i[lane]));
    }

    float p = 1.f;
#pragma unroll
    for (int v = 0; v < 6; ++v) {
        int j = idx[lane * 6 + v];
        int node = (j < N_NODES) ? j : j - N_NODES;
        float d = __shfl(dec, node, 64);
        p *= (j < N_NODES) ? d : (1.0f - d);
    }
    dist[(size_t)row * N_BINS + lane] = p;
}

// ---------------- kernel 2: double-buffered online-rescaled GEMM -----------
// LDS = 2x(As+Bs) = 64 KB exactly -> 2 blocks/CU. stage(i+1) issued right
// after the barrier publishing buf(i); the next barrier's vmcnt(0) drain then
// hits an already-landed prefetch (DMA overlapped with compute+LDS reads).
// dist values come from global (L2-hot) at segment boundaries; no Ds in LDS.
__global__ __launch_bounds__(256, 2) void k_gemm8(
    const unsigned short* __restrict__ xb, const unsigned short* __restrict__ Tt,
    const float* __restrict__ dist, float* __restrict__ part)
{
    __shared__ unsigned short As[2][128 * 64];
    __shared__ unsigned short Bs[2][128 * 64];

    const int b   = blockIdx.x;
    const int xcd = b & 7;
    const int j   = b >> 3;
    const int combo = xcd * 8 + (j >> 4);
    const int mblk  = j & 15;
    const int bm0 = mblk * 128;
    const int bn0 = (combo & 3) * 128;
    const int z   = combo >> 2;
    const int l0  = z * LPS;

    const int t    = threadIdx.x;
    const int lane = t & 63;
    const int wid  = t >> 6;
    const int wm = wid >> 1, wn = wid & 1;
    const int lq = lane >> 4, lr = lane & 15;

    const int srow = t >> 3;   // 0..31 (+ jj*32)
    const int c    = t & 7;    // LDS chunk slot

    f32x4 acc[4][4];
#pragma unroll
    for (int a = 0; a < 4; ++a)
#pragma unroll
        for (int bb = 0; bb < 4; ++bb)
            acc[a][bb] = (f32x4){0.f, 0.f, 0.f, 0.f};

    const int NIT = LPS * 8;   // 32 BK=64 iterations

    // ---- stage iteration `it` into buffer `buf` ----
    // (l = l0 + it/8, i0 = (it%8)*64)
#define STAGE(it_, buf_)                                                      \
    {                                                                         \
        const int l_  = l0 + ((it_) >> 3);                                    \
        const int i0_ = ((it_) & 7) * 64;                                     \
        _Pragma("unroll")                                                     \
        for (int jj = 0; jj < 4; ++jj) {                                      \
            int row = srow + jj * 32;                                         \
            int cg_ = c ^ (row & 7);                                          \
            load_lds16(xb + (size_t)(bm0 + row) * D_DIM + i0_ + cg_ * 8,      \
                       &As[buf_][row * 64 + c * 8]);                          \
            load_lds16(Tt + (size_t)(bn0 + row) * K_TOT + (size_t)l_ * 512    \
                           + i0_ + cg_ * 8,                                   \
                       &Bs[buf_][row * 64 + c * 8]);                          \
        }                                                                     \
    }

    STAGE(0, 0);

    for (int it = 0; it < NIT; ++it) {
        __syncthreads();                     // buf(it) published
        if (it + 1 < NIT) STAGE(it + 1, (it + 1) & 1);   // async prefetch

        // segment-boundary rescale: acc *= d[l-1]/d[l]
        if ((it & 7) == 0 && it > 0) {
            const int l = l0 + (it >> 3);
#pragma unroll
            for (int fm = 0; fm < 4; ++fm)
#pragma unroll
                for (int r = 0; r < 4; ++r) {
                    int m = bm0 + wm * 64 + fm * 16 + lq * 4 + r;
                    f32x2 dd = *(const f32x2*)(dist + (size_t)m * N_BINS + (l - 1));
                    float dp = fmaxf(dd.x, DEPS);
                    float dn = fmaxf(dd.y, DEPS);
                    float ratio = dp * __builtin_amdgcn_rcpf(dn);
#pragma unroll
                    for (int fn = 0; fn < 4; ++fn)
                        acc[fm][fn][r] *= ratio;
                }
        }

        const int buf = it & 1;
#pragma unroll
        for (int ks = 0; ks < 2; ++ks) {
            bf16x8 af[4], bfr[4];
#pragma unroll
            for (int fm = 0; fm < 4; ++fm) {
                int m = wm * 64 + fm * 16 + lr;
                int g = ks * 4 + lq;
                af[fm] = *(const bf16x8*)&As[buf][m * 64 + ((g ^ (m & 7)) * 8)];
            }
#pragma unroll
            for (int fn = 0; fn < 4; ++fn) {
                int n = wn * 64 + fn * 16 + lr;
                int g = ks * 4 + lq;
                bfr[fn] = *(const bf16x8*)&Bs[buf][n * 64 + ((g ^ (n & 7)) * 8)];
            }
#pragma unroll
            for (int fm = 0; fm < 4; ++fm)
#pragma unroll
                for (int fn = 0; fn < 4; ++fn)
                    acc[fm][fn] = __builtin_amdgcn_mfma_f32_16x16x32_bf16(
                        af[fm], bfr[fn], acc[fm][fn], 0, 0, 0);
        }
    }

    // epilogue: multiply by d[last] and store partial
    float* Cp = part + (size_t)z * (B_ROWS * W_DIM);
#pragma unroll
    for (int fm = 0; fm < 4; ++fm)
#pragma unroll
        for (int r = 0; r < 4; ++r) {
            int m = bm0 + wm * 64 + fm * 16 + lq * 4 + r;
            float dl = fmaxf(dist[(size_t)m * N_BINS + (l0 + LPS - 1)], DEPS);
#pragma unroll
            for (int fn = 0; fn < 4; ++fn) {
                int col = bn0 + wn * 64 + fn * 16 + lr;
                Cp[(size_t)m * W_DIM + col] = acc[fm][fn][r] * dl;
            }
        }
#undef STAGE
}

// ---------------- kernel 3: split reduction --------------------------------
__global__ __launch_bounds__(256) void k_reduce(
    const float* __restrict__ part, float* __restrict__ out, int nsplit)
{
    int i = (blockIdx.x * 256 + threadIdx.x) * 4;
    f32x4 s = *(const f32x4*)(part + i);
    for (int p = 1; p < nsplit; ++p)
        s += *(const f32x4*)(part + (size_t)p * (B_ROWS * W_DIM) + i);
    *(f32x4*)(out + i) = s;
}

// ---------------- fallback GEMM (single-split, direct to out) --------------
__global__ __launch_bounds__(256, 2) void k_gemm_bt(
    const float* __restrict__ x, const float* __restrict__ dist,
    const unsigned short* __restrict__ Tt, float* __restrict__ part,
    int kchunk)
{
    __shared__ unsigned short As[128][72];
    __shared__ unsigned short Bs[128][64];

    const int bm0 = blockIdx.x * 128;
    const int bn0 = blockIdx.y * 128;
    const int kbase = blockIdx.z * kchunk;

    const int lane = threadIdx.x & 63;
    const int wid  = threadIdx.x >> 6;
    const int wm = wid >> 1, wn = wid & 1;
    const int lq = lane >> 4, lr = lane & 15;

    f32x4 acc[4][4];
#pragma unroll
    for (int a = 0; a < 4; ++a)
#pragma unroll
        for (int b = 0; b < 4; ++b)
            acc[a][b] = (f32x4){0.f, 0.f, 0.f, 0.f};

    const int iters = kchunk / 64;
    for (int it = 0; it < iters; ++it) {
        const int k0 = kbase + it * 64;
        const int l  = k0 >> 9;
        const int i0 = k0 & 511;
#pragma unroll
        for (int r2 = 0; r2 < 8; ++r2) {
            int id = threadIdx.x + r2 * 256;
            int m  = id >> 4;
            int kc = id & 15;
            float sc = dist[(size_t)(bm0 + m) * N_BINS + l];
            f32x4 v = *(const f32x4*)(x + (size_t)(bm0 + m) * D_DIM + i0 + kc * 4);
            v *= sc;
            unsigned int p0 = (unsigned int)f2bf(v.x) | ((unsigned int)f2bf(v.y) << 16);
            unsigned int p1 = (unsigned int)f2bf(v.z) | ((unsigned int)f2bf(v.w) << 16);
            unsigned int* dp = (unsigned int*)&As[m][kc * 4];
            dp[0] = p0; dp[1] = p1;
        }
#pragma unroll
        for (int r2 = 0; r2 < 4; ++r2) {
            int id = threadIdx.x + r2 * 256;
            int n  = id >> 3;
            int cc = id & 7;
            int cg = cc ^ (n & 7);
            const u16x8 v = *(const u16x8*)(Tt + (size_t)(bn0 + n) * K_TOT + k0 + cg * 8);
            *(u16x8*)&Bs[n][cc * 8] = v;
        }
        __syncthreads();
#pragma unroll
        for (int ks = 0; ks < 2; ++ks) {
            bf16x8 af[4], bfr[4];
#pragma unroll
            for (int fm = 0; fm < 4; ++fm)
                af[fm] = *(const bf16x8*)&As[wm * 64 + fm * 16 + lr][ks * 32 + lq * 8];
#pragma unroll
            for (int fn = 0; fn < 4; ++fn) {
                int nl = wn * 64 + fn * 16 + lr;
                int cs = (ks * 4 + lq) ^ (nl & 7);
                bfr[fn] = *(const bf16x8*)&Bs[nl][cs * 8];
            }
#pragma unroll
            for (int fm = 0; fm < 4; ++fm)
#pragma unroll
                for (int fn = 0; fn < 4; ++fn)
                    acc[fm][fn] = __builtin_amdgcn_mfma_f32_16x16x32_bf16(
                        af[fm], bfr[fn], acc[fm][fn], 0, 0, 0);
        }
        __syncthreads();
    }

    float* Cp = part + (size_t)blockIdx.z * (B_ROWS * W_DIM);
#pragma unroll
    for (int fm = 0; fm < 4; ++fm)
#pragma unroll
        for (int fn = 0; fn < 4; ++fn)
#pragma unroll
            for (int r = 0; r < 4; ++r) {
                int row = bm0 + wm * 64 + fm * 16 + lq * 4 + r;
                int col = bn0 + wn * 64 + fn * 16 + lr;
                Cp[(size_t)row * W_DIM + col] = acc[fm][fn][r];
            }
}

extern "C" void kernel_launch(void* const* d_in, const int* in_sizes, int n_in,
                              void* d_out, int out_size, void* d_ws, size_t ws_size,
                              hipStream_t stream) {
    const float* x   = (const float*)d_in[0];
    const float* ray = (const float*)d_in[1];
    const float* w_i = (const float*)d_in[2];
    const float* b_i = (const float*)d_in[3];
    const float* a_i = (const float*)d_in[4];
    const float* T   = (const float*)d_in[5];
    const int*   idx = (const int*)d_in[6];
    float* out = (float*)d_out;

    char* ws = (char*)d_ws;
    const size_t distBytes = (size_t)B_ROWS * N_BINS * 4;        // 512 KiB
    const size_t xbBytes   = (size_t)B_ROWS * D_DIM * 2;         // 2 MiB
    const size_t ttBytes   = (size_t)W_DIM * K_TOT * 2;          // 32 MiB
    const size_t partBytes = (size_t)B_ROWS * W_DIM * 4;         // 4 MiB per split

    float*          dist = (float*)ws;
    unsigned short* xb   = (unsigned short*)(ws + distBytes);
    unsigned short* Tt   = (unsigned short*)(ws + distBytes + xbBytes);

    if (ws_size >= distBytes + xbBytes + ttBytes + (size_t)NSPLIT * partBytes) {
        // -------- path A: dbuf online-rescaled dist-fold GEMM --------
        float* part = (float*)(ws + distBytes + xbBytes + ttBytes);

        k_pre<<<4096 + 512, 256, 0, stream>>>(x, ray, w_i, b_i, a_i, idx, T,
                                              dist, xb, Tt);
        k_gemm8<<<1024, 256, 0, stream>>>(xb, Tt, dist, part);
        k_reduce<<<(B_ROWS * W_DIM) / (256 * 4), 256, 0, stream>>>(part, out, NSPLIT);
    } else if (ws_size >= distBytes + xbBytes + ttBytes) {
        // -------- path B: single-split direct-to-out --------
        k_pre<<<4096 + 512, 256, 0, stream>>>(x, ray, w_i, b_i, a_i, idx, T,
                                              dist, xb, Tt);
        k_gemm_bt<<<dim3(16, 4, 1), 256, 0, stream>>>(x, dist, Tt, out, K_TOT);
    }
}

// Round 10
// 191.197 us; speedup vs baseline: 3.4371x; 1.0483x over previous
//
#include <hip/hip_runtime.h>
#include <math.h>

typedef float  f32x4  __attribute__((ext_vector_type(4)));
typedef float  f32x2  __attribute__((ext_vector_type(2)));
typedef short  bf16x8 __attribute__((ext_vector_type(8)));
typedef unsigned short u16x8 __attribute__((ext_vector_type(8)));
typedef unsigned short u16x4 __attribute__((ext_vector_type(4)));

#define B_ROWS 2048
#define D_DIM  512
#define W_DIM  512
#define N_NODES 63
#define N_BINS  64
#define K_TOT   32768   // 64 * 512
#define NSPLIT  8       // 8 l's per z-slot -> grid 512 = exactly 2 blocks/CU
#define LPS     (N_BINS / NSPLIT)   // 8
#define DEPS    1e-12f

__device__ __forceinline__ unsigned short f2bf(float f) {
    union { float f; unsigned int u; } v; v.f = f;
    unsigned int u = v.u;
    return (unsigned short)((u + 0x7fffu + ((u >> 16) & 1u)) >> 16);
}

__device__ __forceinline__ float sigmoidf_(float z) {
    return 1.0f / (1.0f + expf(-z));
}

__device__ __forceinline__ void load_lds16(const void* g, void* l) {
    __builtin_amdgcn_global_load_lds(
        (const __attribute__((address_space(1))) unsigned int*)g,
        (__attribute__((address_space(3))) unsigned int*)l,
        16, 0, 0);
}

// ---------------- kernel 1: fused prep (dist + xb) AND transpose -----------
__global__ __launch_bounds__(256) void k_pre(
    const float* __restrict__ x, const float* __restrict__ ray,
    const float* __restrict__ w_i, const float* __restrict__ b_i,
    const float* __restrict__ a_i, const int* __restrict__ idx,
    const float* __restrict__ T,
    float* __restrict__ dist, unsigned short* __restrict__ xb,
    unsigned short* __restrict__ Tt)
{
    __shared__ float tile[64][65];
    const int bid = blockIdx.x;
    const int t   = threadIdx.x;

    if (bid < 4096) {
        const int i0 = (bid & 7) * 64;
        const int w0 = ((bid >> 3) & 7) * 64;
        const int l  = bid >> 6;

        const int w4 = (t & 15) * 4;
        const int ir = t >> 4;
        const float* src = T + ((size_t)(l * 512 + i0)) * 512 + w0;
#pragma unroll
        for (int p = 0; p < 4; ++p) {
            int i = ir + p * 16;
            f32x4 v = *(const f32x4*)(src + (size_t)i * 512 + w4);
            tile[i][w4 + 0] = v.x; tile[i][w4 + 1] = v.y;
            tile[i][w4 + 2] = v.z; tile[i][w4 + 3] = v.w;
        }
        __syncthreads();
#pragma unroll
        for (int rep = 0; rep < 2; ++rep) {
            int id = t + rep * 256;
            int w  = id >> 3;
            int c  = id & 7;
            u16x8 o;
#pragma unroll
            for (int j = 0; j < 8; ++j) o[j] = f2bf(tile[c * 8 + j][w]);
            *(u16x8*)(Tt + (size_t)(w0 + w) * K_TOT + l * 512 + i0 + c * 8) = o;
        }
        return;
    }

    const int pb   = bid - 4096;
    const int wid  = t >> 6;
    const int lane = t & 63;
    const int row  = pb * 4 + wid;
    const float* xr = x + (size_t)row * D_DIM;

    float dotv = 0.f, xx = 0.f, rr = 0.f;
#pragma unroll
    for (int j = 0; j < 2; ++j) {
        f32x4 xv = *(const f32x4*)(xr  + j * 256 + lane * 4);
        f32x4 rv = *(const f32x4*)(ray + j * 256 + lane * 4);
        dotv += xv.x * rv.x + xv.y * rv.y + xv.z * rv.z + xv.w * rv.w;
        xx   += xv.x * xv.x + xv.y * xv.y + xv.z * xv.z + xv.w * xv.w;
        rr   += rv.x * rv.x + rv.y * rv.y + rv.z * rv.z + rv.w * rv.w;
        u16x4 o;
        o[0] = f2bf(xv.x); o[1] = f2bf(xv.y); o[2] = f2bf(xv.z); o[3] = f2bf(xv.w);
        *(u16x4*)(xb + (size_t)row * D_DIM + j * 256 + lane * 4) = o;
    }
#pragma unroll
    for (int off = 1; off < 64; off <<= 1) {
        dotv += __shfl_xor(dotv, off, 64);
        xx   += __shfl_xor(xx,   off, 64);
        rr   += __shfl_xor(rr,   off, 64);
    }
    float xn = fmaxf(sqrtf(xx), 1e-8f);
    float rn = fmaxf(sqrtf(rr), 1e-8f);
    float cosv = dotv / (xn * rn);
    cosv = fminf(1.f, fmaxf(-1.f, cosv));
    float angle = acosf(cosv) * 0.31830988618379067f;

    float dec = 0.f;
    if (lane < N_NODES) {
        float sw = sigmoidf_(w_i[lane]);
        float sb = sigmoidf_(b_i[lane]);
        float nf = (0.5f + sw) * angle - sb;
        dec = sigmoidf_(nf * (1.0f + a_i[lane]));
    }

    float p = 1.f;
#pragma unroll
    for (int v = 0; v < 6; ++v) {
        int j = idx[lane * 6 + v];
        int node = (j < N_NODES) ? j : j - N_NODES;
        float d = __shfl(dec, node, 64);
        p *= (j < N_NODES) ? d : (1.0f - d);
    }
    dist[(size_t)row * N_BINS + lane] = p;
}

// ---------------- kernel 2: double-buffered online-rescaled GEMM -----------
// NSPLIT=8: grid 512 = 2 blocks/CU exactly (one residency round), 64 BK=64
// iters per block. LDS 64 KB (2x dbuf). ~92% of LDS-BW structural limit.
__global__ __launch_bounds__(256, 2) void k_gemm9(
    const unsigned short* __restrict__ xb, const unsigned short* __restrict__ Tt,
    const float* __restrict__ dist, float* __restrict__ part)
{
    __shared__ unsigned short As[2][128 * 64];
    __shared__ unsigned short Bs[2][128 * 64];

    const int b   = blockIdx.x;              // 0..511
    const int xcd = b & 7;
    const int j   = b >> 3;                  // 0..63
    const int combo = xcd * 4 + (j >> 4);    // 0..31  (4 combos per XCD)
    const int mblk  = j & 15;
    const int bm0 = mblk * 128;
    const int bn0 = (combo & 3) * 128;
    const int z   = combo >> 2;              // 0..7
    const int l0  = z * LPS;

    const int t    = threadIdx.x;
    const int lane = t & 63;
    const int wid  = t >> 6;
    const int wm = wid >> 1, wn = wid & 1;
    const int lq = lane >> 4, lr = lane & 15;

    const int srow = t >> 3;   // 0..31 (+ jj*32)
    const int c    = t & 7;    // LDS chunk slot

    f32x4 acc[4][4];
#pragma unroll
    for (int a = 0; a < 4; ++a)
#pragma unroll
        for (int bb = 0; bb < 4; ++bb)
            acc[a][bb] = (f32x4){0.f, 0.f, 0.f, 0.f};

    const int NIT = LPS * 8;   // 64 BK=64 iterations

#define STAGE(it_, buf_)                                                      \
    {                                                                         \
        const int l_  = l0 + ((it_) >> 3);                                    \
        const int i0_ = ((it_) & 7) * 64;                                     \
        _Pragma("unroll")                                                     \
        for (int jj = 0; jj < 4; ++jj) {                                      \
            int row = srow + jj * 32;                                         \
            int cg_ = c ^ (row & 7);                                          \
            load_lds16(xb + (size_t)(bm0 + row) * D_DIM + i0_ + cg_ * 8,      \
                       &As[buf_][row * 64 + c * 8]);                          \
            load_lds16(Tt + (size_t)(bn0 + row) * K_TOT + (size_t)l_ * 512    \
                           + i0_ + cg_ * 8,                                   \
                       &Bs[buf_][row * 64 + c * 8]);                          \
        }                                                                     \
    }

    STAGE(0, 0);

    for (int it = 0; it < NIT; ++it) {
        __syncthreads();                     // buf(it) published
        if (it + 1 < NIT) STAGE(it + 1, (it + 1) & 1);   // async prefetch

        // segment-boundary rescale: acc *= d[l-1]/d[l]
        if ((it & 7) == 0 && it > 0) {
            const int l = l0 + (it >> 3);
#pragma unroll
            for (int fm = 0; fm < 4; ++fm)
#pragma unroll
                for (int r = 0; r < 4; ++r) {
                    int m = bm0 + wm * 64 + fm * 16 + lq * 4 + r;
                    f32x2 dd = *(const f32x2*)(dist + (size_t)m * N_BINS + (l - 1));
                    float dp = fmaxf(dd.x, DEPS);
                    float dn = fmaxf(dd.y, DEPS);
                    float ratio = dp * __builtin_amdgcn_rcpf(dn);
#pragma unroll
                    for (int fn = 0; fn < 4; ++fn)
                        acc[fm][fn][r] *= ratio;
                }
        }

        const int buf = it & 1;
#pragma unroll
        for (int ks = 0; ks < 2; ++ks) {
            bf16x8 af[4], bfr[4];
#pragma unroll
            for (int fm = 0; fm < 4; ++fm) {
                int m = wm * 64 + fm * 16 + lr;
                int g = ks * 4 + lq;
                af[fm] = *(const bf16x8*)&As[buf][m * 64 + ((g ^ (m & 7)) * 8)];
            }
#pragma unroll
            for (int fn = 0; fn < 4; ++fn) {
                int n = wn * 64 + fn * 16 + lr;
                int g = ks * 4 + lq;
                bfr[fn] = *(const bf16x8*)&Bs[buf][n * 64 + ((g ^ (n & 7)) * 8)];
            }
#pragma unroll
            for (int fm = 0; fm < 4; ++fm)
#pragma unroll
                for (int fn = 0; fn < 4; ++fn)
                    acc[fm][fn] = __builtin_amdgcn_mfma_f32_16x16x32_bf16(
                        af[fm], bfr[fn], acc[fm][fn], 0, 0, 0);
        }
    }

    // epilogue: multiply by d[last] and store partial
    float* Cp = part + (size_t)z * (B_ROWS * W_DIM);
#pragma unroll
    for (int fm = 0; fm < 4; ++fm)
#pragma unroll
        for (int r = 0; r < 4; ++r) {
            int m = bm0 + wm * 64 + fm * 16 + lq * 4 + r;
            float dl = fmaxf(dist[(size_t)m * N_BINS + (l0 + LPS - 1)], DEPS);
#pragma unroll
            for (int fn = 0; fn < 4; ++fn) {
                int col = bn0 + wn * 64 + fn * 16 + lr;
                Cp[(size_t)m * W_DIM + col] = acc[fm][fn][r] * dl;
            }
        }
#undef STAGE
}

// ---------------- kernel 3: split reduction --------------------------------
__global__ __launch_bounds__(256) void k_reduce(
    const float* __restrict__ part, float* __restrict__ out, int nsplit)
{
    int i = (blockIdx.x * 256 + threadIdx.x) * 4;
    f32x4 s = *(const f32x4*)(part + i);
    for (int p = 1; p < nsplit; ++p)
        s += *(const f32x4*)(part + (size_t)p * (B_ROWS * W_DIM) + i);
    *(f32x4*)(out + i) = s;
}

// ---------------- fallback GEMM (single-split, direct to out) --------------
__global__ __launch_bounds__(256, 2) void k_gemm_bt(
    const float* __restrict__ x, const float* __restrict__ dist,
    const unsigned short* __restrict__ Tt, float* __restrict__ part,
    int kchunk)
{
    __shared__ unsigned short As[128][72];
    __shared__ unsigned short Bs[128][64];

    const int bm0 = blockIdx.x * 128;
    const int bn0 = blockIdx.y * 128;
    const int kbase = blockIdx.z * kchunk;

    const int lane = threadIdx.x & 63;
    const int wid  = threadIdx.x >> 6;
    const int wm = wid >> 1, wn = wid & 1;
    const int lq = lane >> 4, lr = lane & 15;

    f32x4 acc[4][4];
#pragma unroll
    for (int a = 0; a < 4; ++a)
#pragma unroll
        for (int b = 0; b < 4; ++b)
            acc[a][b] = (f32x4){0.f, 0.f, 0.f, 0.f};

    const int iters = kchunk / 64;
    for (int it = 0; it < iters; ++it) {
        const int k0 = kbase + it * 64;
        const int l  = k0 >> 9;
        const int i0 = k0 & 511;
#pragma unroll
        for (int r2 = 0; r2 < 8; ++r2) {
            int id = threadIdx.x + r2 * 256;
            int m  = id >> 4;
            int kc = id & 15;
            float sc = dist[(size_t)(bm0 + m) * N_BINS + l];
            f32x4 v = *(const f32x4*)(x + (size_t)(bm0 + m) * D_DIM + i0 + kc * 4);
            v *= sc;
            unsigned int p0 = (unsigned int)f2bf(v.x) | ((unsigned int)f2bf(v.y) << 16);
            unsigned int p1 = (unsigned int)f2bf(v.z) | ((unsigned int)f2bf(v.w) << 16);
            unsigned int* dp = (unsigned int*)&As[m][kc * 4];
            dp[0] = p0; dp[1] = p1;
        }
#pragma unroll
        for (int r2 = 0; r2 < 4; ++r2) {
            int id = threadIdx.x + r2 * 256;
            int n  = id >> 3;
            int cc = id & 7;
            int cg = cc ^ (n & 7);
            const u16x8 v = *(const u16x8*)(Tt + (size_t)(bn0 + n) * K_TOT + k0 + cg * 8);
            *(u16x8*)&Bs[n][cc * 8] = v;
        }
        __syncthreads();
#pragma unroll
        for (int ks = 0; ks < 2; ++ks) {
            bf16x8 af[4], bfr[4];
#pragma unroll
            for (int fm = 0; fm < 4; ++fm)
                af[fm] = *(const bf16x8*)&As[wm * 64 + fm * 16 + lr][ks * 32 + lq * 8];
#pragma unroll
            for (int fn = 0; fn < 4; ++fn) {
                int nl = wn * 64 + fn * 16 + lr;
                int cs = (ks * 4 + lq) ^ (nl & 7);
                bfr[fn] = *(const bf16x8*)&Bs[nl][cs * 8];
            }
#pragma unroll
            for (int fm = 0; fm < 4; ++fm)
#pragma unroll
                for (int fn = 0; fn < 4; ++fn)
                    acc[fm][fn] = __builtin_amdgcn_mfma_f32_16x16x32_bf16(
                        af[fm], bfr[fn], acc[fm][fn], 0, 0, 0);
        }
        __syncthreads();
    }

    float* Cp = part + (size_t)blockIdx.z * (B_ROWS * W_DIM);
#pragma unroll
    for (int fm = 0; fm < 4; ++fm)
#pragma unroll
        for (int fn = 0; fn < 4; ++fn)
#pragma unroll
            for (int r = 0; r < 4; ++r) {
                int row = bm0 + wm * 64 + fm * 16 + lq * 4 + r;
                int col = bn0 + wn * 64 + fn * 16 + lr;
                Cp[(size_t)row * W_DIM + col] = acc[fm][fn][r];
            }
}

extern "C" void kernel_launch(void* const* d_in, const int* in_sizes, int n_in,
                              void* d_out, int out_size, void* d_ws, size_t ws_size,
                              hipStream_t stream) {
    const float* x   = (const float*)d_in[0];
    const float* ray = (const float*)d_in[1];
    const float* w_i = (const float*)d_in[2];
    const float* b_i = (const float*)d_in[3];
    const float* a_i = (const float*)d_in[4];
    const float* T   = (const float*)d_in[5];
    const int*   idx = (const int*)d_in[6];
    float* out = (float*)d_out;

    char* ws = (char*)d_ws;
    const size_t distBytes = (size_t)B_ROWS * N_BINS * 4;        // 512 KiB
    const size_t xbBytes   = (size_t)B_ROWS * D_DIM * 2;         // 2 MiB
    const size_t ttBytes   = (size_t)W_DIM * K_TOT * 2;          // 32 MiB
    const size_t partBytes = (size_t)B_ROWS * W_DIM * 4;         // 4 MiB per split

    float*          dist = (float*)ws;
    unsigned short* xb   = (unsigned short*)(ws + distBytes);
    unsigned short* Tt   = (unsigned short*)(ws + distBytes + xbBytes);

    if (ws_size >= distBytes + xbBytes + ttBytes + (size_t)NSPLIT * partBytes) {
        // -------- path A: dbuf online-rescaled dist-fold GEMM, NSPLIT=8 ----
        float* part = (float*)(ws + distBytes + xbBytes + ttBytes);

        k_pre<<<4096 + 512, 256, 0, stream>>>(x, ray, w_i, b_i, a_i, idx, T,
                                              dist, xb, Tt);
        k_gemm9<<<512, 256, 0, stream>>>(xb, Tt, dist, part);
        k_reduce<<<(B_ROWS * W_DIM) / (256 * 4), 256, 0, stream>>>(part, out, NSPLIT);
    } else if (ws_size >= distBytes + xbBytes + ttBytes) {
        // -------- path B: single-split direct-to-out --------
        k_pre<<<4096 + 512, 256, 0, stream>>>(x, ray, w_i, b_i, a_i, idx, T,
                                              dist, xb, Tt);
        k_gemm_bt<<<dim3(16, 4, 1), 256, 0, stream>>>(x, dist, Tt, out, K_TOT);
    }
}